// Round 1
// baseline (2313.992 us; speedup 1.0000x reference)
//
#include <hip/hip_runtime.h>
#include <hip/hip_bf16.h>

// Sizes (compile-time constants from the reference)
// V=50257, D=1024, H=16, FF=4096, L=2, N=2000, K=20, B=4, S=256
#define NVT 786   // ceil(50257/64) vocab tiles (fp32 fallback path)
#define NV2 393   // ceil(50257/128) vocab tiles (MFMA path)
#define NTOK 1020 // B*(S-1) CE tokens

typedef __attribute__((ext_vector_type(8))) __bf16 bf16x8;
typedef __attribute__((ext_vector_type(4))) float f32x4;

__device__ __forceinline__ float block_sum(float v, float* red) {
    int tid = threadIdx.x;
    red[tid] = v;
    __syncthreads();
    for (int s = 128; s > 0; s >>= 1) {
        if (tid < s) red[tid] += red[tid + s];
        __syncthreads();
    }
    float r = red[0];
    __syncthreads();
    return r;
}

__device__ __forceinline__ unsigned short f2bf(float f) {
    union { float f; unsigned int u; } v; v.f = f;
    unsigned int r = v.u + 0x7fffu + ((v.u >> 16) & 1u);
    return (unsigned short)(r >> 16);
}

// ---- fp32 -> bf16 (RNE), vectorized, grid-stride over float4s
__global__ __launch_bounds__(256) void cvt_bf16_k(const float* __restrict__ in,
                                                  unsigned short* __restrict__ out,
                                                  int n4) {
    int i = blockIdx.x * 256 + threadIdx.x;
    int stride = gridDim.x * 256;
    for (; i < n4; i += stride) {
        float4 v = ((const float4*)in)[i];
        ushort4 o;
        o.x = f2bf(v.x); o.y = f2bf(v.y); o.z = f2bf(v.z); o.w = f2bf(v.w);
        ((ushort4*)out)[i] = o;
    }
}

// ---- embedding gather: x[row,:] = emb[inputs[row],:]  (1024 rows of 1024)
__global__ __launch_bounds__(256) void embed_k(const int* __restrict__ inp,
                                               const float* __restrict__ emb,
                                               float* __restrict__ x) {
    int row = blockIdx.x;
    int tok = inp[row];
    int d = threadIdx.x * 4;
    float4 v = *(const float4*)(emb + (size_t)tok * 1024 + d);
    *(float4*)(x + (size_t)row * 1024 + d) = v;
}

// ---- copy last seq position per batch: xl[b,:] = x[b*256+255,:]
__global__ __launch_bounds__(256) void copy_last_k(const float* __restrict__ x,
                                                   float* __restrict__ xl) {
    int b = blockIdx.x;
    int d = threadIdx.x * 4;
    float4 v = *(const float4*)(x + (size_t)(b * 256 + 255) * 1024 + d);
    *(float4*)(xl + (size_t)b * 1024 + d) = v;
}

// ---- generic NT gemm: C[M,N] = A[M,K] * W[N,K]^T + bias, opt relu
// M%64==0, N%64==0, K%16==0. block 256, tile 64x64, 4x4 per thread.
__global__ __launch_bounds__(256) void gemm_nt_k(const float* __restrict__ A,
                                                 const float* __restrict__ W,
                                                 const float* __restrict__ bias,
                                                 float* __restrict__ C,
                                                 int N, int K, int relu) {
    __shared__ alignas(16) float As[16][64];
    __shared__ alignas(16) float Ws[16][64];
    int tid = threadIdx.x;
    int bm = blockIdx.y << 6, bn = blockIdx.x << 6;
    int tx = tid & 15, ty = tid >> 4;
    int lrow = tid >> 2, lk4 = (tid & 3) << 2;
    const float* Ap = A + (size_t)(bm + lrow) * K + lk4;
    const float* Wp = W + (size_t)(bn + lrow) * K + lk4;
    float acc[4][4] = {};
    for (int k0 = 0; k0 < K; k0 += 16) {
        float4 av = *(const float4*)(Ap + k0);
        float4 wv = *(const float4*)(Wp + k0);
        As[lk4 + 0][lrow] = av.x; As[lk4 + 1][lrow] = av.y;
        As[lk4 + 2][lrow] = av.z; As[lk4 + 3][lrow] = av.w;
        Ws[lk4 + 0][lrow] = wv.x; Ws[lk4 + 1][lrow] = wv.y;
        Ws[lk4 + 2][lrow] = wv.z; Ws[lk4 + 3][lrow] = wv.w;
        __syncthreads();
#pragma unroll
        for (int k = 0; k < 16; ++k) {
            float4 a4 = *(const float4*)&As[k][ty << 2];
            float4 b4 = *(const float4*)&Ws[k][tx << 2];
            float a[4] = {a4.x, a4.y, a4.z, a4.w};
            float b[4] = {b4.x, b4.y, b4.z, b4.w};
#pragma unroll
            for (int i = 0; i < 4; ++i)
#pragma unroll
                for (int j = 0; j < 4; ++j) acc[i][j] += a[i] * b[j];
        }
        __syncthreads();
    }
#pragma unroll
    for (int i = 0; i < 4; ++i) {
        int m = bm + (ty << 2) + i;
#pragma unroll
        for (int j = 0; j < 4; ++j) {
            int n = bn + (tx << 2) + j;
            float v = acc[i][j] + bias[n];
            if (relu) v = fmaxf(v, 0.0f);
            C[(size_t)m * N + n] = v;
        }
    }
}

// ---- loc-layer attention, query = last position only. grid = B*H = 64.
__global__ __launch_bounds__(256) void attn_last_k(const float* __restrict__ qkv,
                                                   float* __restrict__ out) {
    int b = blockIdx.x >> 4, h = blockIdx.x & 15;
    int tid = threadIdx.x;
    __shared__ float qs[64];
    __shared__ float sc[256];
    __shared__ float red[256];
    if (tid < 64) qs[tid] = qkv[(size_t)(b * 256 + 255) * 3072 + h * 64 + tid];
    __syncthreads();
    const float* kp = qkv + (size_t)(b * 256 + tid) * 3072 + 1024 + h * 64;
    float s = 0;
    for (int d = 0; d < 64; ++d) s += qs[d] * kp[d];
    s *= 0.125f;
    red[tid] = s;
    __syncthreads();
    for (int st = 128; st; st >>= 1) { if (tid < st) red[tid] = fmaxf(red[tid], red[tid + st]); __syncthreads(); }
    float mx = red[0];
    __syncthreads();
    float e = __expf(s - mx);
    red[tid] = e;
    __syncthreads();
    for (int st = 128; st; st >>= 1) { if (tid < st) red[tid] += red[tid + st]; __syncthreads(); }
    float inv = 1.0f / red[0];
    __syncthreads();
    sc[tid] = e * inv;
    __syncthreads();
    if (tid < 64) {
        const float* vp = qkv + 2048 + h * 64 + tid;
        float o = 0;
        for (int j = 0; j < 256; ++j) o += sc[j] * vp[(size_t)(b * 256 + j) * 3072];
        out[(size_t)b * 1024 + h * 64 + tid] = o;
    }
}

// ---- small-M (M=4) gemm: out[4,N] = A[4,K] * W[N,K]^T + bias; one wave per n
__global__ __launch_bounds__(256) void rowgemm_k(const float* __restrict__ A,
                                                 const float* __restrict__ W,
                                                 const float* __restrict__ bias,
                                                 float* __restrict__ out,
                                                 int N, int K, int relu) {
    int n = blockIdx.x * 4 + (threadIdx.x >> 6);
    if (n >= N) return;
    int lane = threadIdx.x & 63;
    const float* Wp = W + (size_t)n * K;
    float a0 = 0, a1 = 0, a2 = 0, a3 = 0;
    for (int k = lane * 4; k < K; k += 256) {
        float4 wv = *(const float4*)(Wp + k);
        float4 x0 = *(const float4*)(A + k);
        float4 x1 = *(const float4*)(A + K + k);
        float4 x2 = *(const float4*)(A + 2 * K + k);
        float4 x3 = *(const float4*)(A + 3 * K + k);
        a0 += wv.x * x0.x + wv.y * x0.y + wv.z * x0.z + wv.w * x0.w;
        a1 += wv.x * x1.x + wv.y * x1.y + wv.z * x1.z + wv.w * x1.w;
        a2 += wv.x * x2.x + wv.y * x2.y + wv.z * x2.z + wv.w * x2.w;
        a3 += wv.x * x3.x + wv.y * x3.y + wv.z * x3.z + wv.w * x3.w;
    }
    for (int o = 32; o; o >>= 1) {
        a0 += __shfl_down(a0, o); a1 += __shfl_down(a1, o);
        a2 += __shfl_down(a2, o); a3 += __shfl_down(a3, o);
    }
    if (lane == 0) {
        float bs = bias[n];
        float v0 = a0 + bs, v1 = a1 + bs, v2 = a2 + bs, v3 = a3 + bs;
        if (relu) { v0 = fmaxf(v0, 0.f); v1 = fmaxf(v1, 0.f); v2 = fmaxf(v2, 0.f); v3 = fmaxf(v3, 0.f); }
        out[n] = v0; out[N + n] = v1; out[2 * N + n] = v2; out[3 * N + n] = v3;
    }
}

// ---- out[row,:] = LN(a[row,:] + r[row,:]) * g + b, then *scale. D=1024. grid=rows
__global__ __launch_bounds__(256) void add_ln_k(const float* __restrict__ a,
                                                const float* __restrict__ r,
                                                const float* __restrict__ g,
                                                const float* __restrict__ bb,
                                                float* __restrict__ out, float scale) {
    __shared__ float red[256];
    int tid = threadIdx.x;
    size_t base = (size_t)blockIdx.x * 1024 + tid * 4;
    float4 av = *(const float4*)(a + base);
    float4 rv = *(const float4*)(r + base);
    float v0 = av.x + rv.x, v1 = av.y + rv.y, v2 = av.z + rv.z, v3 = av.w + rv.w;
    float mean = block_sum(v0 + v1 + v2 + v3, red) * (1.0f / 1024.0f);
    float d0 = v0 - mean, d1 = v1 - mean, d2 = v2 - mean, d3 = v3 - mean;
    float var = block_sum(d0 * d0 + d1 * d1 + d2 * d2 + d3 * d3, red) * (1.0f / 1024.0f);
    float rstd = rsqrtf(var + 1e-5f);
    float4 gv = *(const float4*)(g + tid * 4);
    float4 bv = *(const float4*)(bb + tid * 4);
    float4 o;
    o.x = (d0 * rstd * gv.x + bv.x) * scale;
    o.y = (d1 * rstd * gv.y + bv.y) * scale;
    o.z = (d2 * rstd * gv.z + bv.z) * scale;
    o.w = (d3 * rstd * gv.w + bv.w) * scale;
    *(float4*)(out + base) = o;
}

// ---- gate stats: fm, total, imp, top-20 -> jw; also writes weights to out[1..8000]
__global__ __launch_bounds__(256) void gate_stats_k(const float* __restrict__ wf,
                                                    const float* __restrict__ noise,
                                                    float* __restrict__ jw,
                                                    float* __restrict__ impp,
                                                    float* __restrict__ out) {
    int tid = threadIdx.x;
    __shared__ float fm[2000];
    __shared__ float tot[2000];
    __shared__ float red[256];
    __shared__ int redi[256];
    __shared__ float topv[20];
    for (int n = tid; n < 2000; n += 256)
        fm[n] = 0.25f * (wf[n] + wf[2000 + n] + wf[4000 + n] + wf[6000 + n]);
    __syncthreads();
    float p = 0;
    for (int n = tid; n < 2000; n += 256) p += fm[n];
    float mean_fm = block_sum(p, red) * (1.0f / 2000.0f);
    p = 0;
    for (int n = tid; n < 2000; n += 256) { float d = fm[n] - mean_fm; p += d * d; }
    float std_fm = sqrtf(block_sum(p, red) * (1.0f / 1999.0f));
    for (int n = tid; n < 2000; n += 256) tot[n] = fm[n] + noise[n] * std_fm;
    __syncthreads();
    p = 0;
    for (int n = tid; n < 2000; n += 256) p += tot[n];
    float mean_t = block_sum(p, red) * (1.0f / 2000.0f);
    p = 0;
    for (int n = tid; n < 2000; n += 256) { float d = tot[n] - mean_t; p += d * d; }
    float var_t = block_sum(p, red) * (1.0f / 1999.0f);
    float imp = 0.1f * var_t / (mean_t * mean_t);
    // top-20 by repeated argmax on a scratch copy (reuse fm)
    for (int n = tid; n < 2000; n += 256) fm[n] = tot[n];
    __syncthreads();
    for (int it = 0; it < 20; ++it) {
        float bv = -INFINITY; int bi = 0x7fffffff;
        for (int n = tid; n < 2000; n += 256) {
            float v = fm[n];
            if (v > bv || (v == bv && n < bi)) { bv = v; bi = n; }
        }
        red[tid] = bv; redi[tid] = bi;
        __syncthreads();
        for (int s = 128; s; s >>= 1) {
            if (tid < s) {
                float v2 = red[tid + s]; int i2 = redi[tid + s];
                if (v2 > red[tid] || (v2 == red[tid] && i2 < redi[tid])) { red[tid] = v2; redi[tid] = i2; }
            }
            __syncthreads();
        }
        if (tid == 0) { topv[it] = red[0]; fm[redi[0]] = -INFINITY; }
        __syncthreads();
    }
    if (tid == 0) {
        float mx = topv[0];
        float s = 0;
        for (int i = 0; i < 20; ++i) s += __expf(topv[i] - mx);
        float inv = 1.0f / s;
        for (int i = 0; i < 20; ++i) jw[i] = __expf(topv[i] - mx) * inv;
        impp[0] = imp;
    }
    for (int idx = tid; idx < 8000; idx += 256) out[1 + idx] = wf[idx];
}

// ---- query_hidden = sum_i jw[i] * responses[i]
__global__ __launch_bounds__(256) void qh_k(const float* __restrict__ resp,
                                            const float* __restrict__ jw,
                                            float* __restrict__ x) {
    __shared__ float jws[20];
    int tid = threadIdx.x;
    if (tid < 20) jws[tid] = jw[tid];
    __syncthreads();
    size_t e0 = ((size_t)blockIdx.x * 256 + tid) * 4;
    float a0 = 0, a1 = 0, a2 = 0, a3 = 0;
    for (int i = 0; i < 20; ++i) {
        float4 r = *(const float4*)(resp + (size_t)i * 1048576 + e0);
        float w = jws[i];
        a0 += w * r.x; a1 += w * r.y; a2 += w * r.z; a3 += w * r.w;
    }
    float4 o = {a0, a1, a2, a3};
    *(float4*)(x + e0) = o;
}

// ---- full attention scores+softmax per (b,h,32-row tile). grid = 4*16*8 = 512
__global__ __launch_bounds__(256) void attn_scores_k(const float* __restrict__ qkv,
                                                     float* __restrict__ aw) {
    int bx = blockIdx.x;
    int it = bx & 7, h = (bx >> 3) & 15, b = bx >> 7;
    int tid = threadIdx.x;
    __shared__ float Qs[32][64];
    __shared__ float Ks[64][64];
    __shared__ float Ss[32][256];
    int i0 = it * 32;
    for (int r = 0; r < 8; ++r) {
        int e = tid + 256 * r;
        int i = e >> 6, d = e & 63;
        Qs[i][d] = qkv[(size_t)(b * 256 + i0 + i) * 3072 + h * 64 + d];
    }
    int i = tid >> 3, jg = tid & 7;
    for (int jt = 0; jt < 4; ++jt) {
        __syncthreads();
        for (int r = 0; r < 16; ++r) {
            int e = tid + 256 * r;
            int j = e >> 6, d = e & 63;
            Ks[j][d] = qkv[(size_t)(b * 256 + jt * 64 + j) * 3072 + 1024 + h * 64 + d];
        }
        __syncthreads();
        for (int jj = 0; jj < 8; ++jj) {
            int jl = jg * 8 + jj;
            float s = 0;
            for (int d = 0; d < 64; ++d) s += Qs[i][d] * Ks[jl][d];
            Ss[i][jt * 64 + jl] = s * 0.125f;
        }
    }
    // row softmax by the row's 8 lanes (same wave -> lockstep, no barrier needed)
    float m = -INFINITY;
    for (int c = jg; c < 256; c += 8) m = fmaxf(m, Ss[i][c]);
    for (int o = 4; o; o >>= 1) m = fmaxf(m, __shfl_down(m, o, 8));
    m = __shfl(m, 0, 8);
    float sum = 0;
    for (int c = jg; c < 256; c += 8) { float e = __expf(Ss[i][c] - m); Ss[i][c] = e; sum += e; }
    for (int o = 4; o; o >>= 1) sum += __shfl_down(sum, o, 8);
    sum = __shfl(sum, 0, 8);
    float inv = 1.0f / sum;
    size_t base = ((size_t)(b * 16 + h) * 256 + (i0 + i)) * 256;
    for (int c = jg; c < 256; c += 8) aw[base + c] = Ss[i][c] * inv;
}

// ---- attention A@V per (b,h,32-row tile). grid = 512
__global__ __launch_bounds__(256) void attn_av_k(const float* __restrict__ qkv,
                                                 const float* __restrict__ aw,
                                                 float* __restrict__ out) {
    int bx = blockIdx.x;
    int it = bx & 7, h = (bx >> 3) & 15, b = bx >> 7;
    int tid = threadIdx.x;
    __shared__ float As[32][256];
    __shared__ float Vs[64][64];
    int i0 = it * 32;
    for (int r = 0; r < 32; ++r) {
        int e = tid + 256 * r;
        int i = e >> 8, c = e & 255;
        As[i][c] = aw[((size_t)(b * 16 + h) * 256 + i0 + i) * 256 + c];
    }
    int i = tid >> 3, dg = tid & 7;
    float acc[8] = {};
    for (int jt = 0; jt < 4; ++jt) {
        __syncthreads();
        for (int r = 0; r < 16; ++r) {
            int e = tid + 256 * r;
            int j = e >> 6, d = e & 63;
            Vs[j][d] = qkv[(size_t)(b * 256 + jt * 64 + j) * 3072 + 2048 + h * 64 + d];
        }
        __syncthreads();
        for (int jl = 0; jl < 64; ++jl) {
            float a = As[i][jt * 64 + jl];
#pragma unroll
            for (int dd = 0; dd < 8; ++dd) acc[dd] += a * Vs[jl][dg * 8 + dd];
        }
    }
    size_t ob = (size_t)(b * 256 + i0 + i) * 1024 + h * 64 + dg * 8;
#pragma unroll
    for (int dd = 0; dd < 8; ++dd) out[ob + dd] = acc[dd];
}

// ---- MFMA decoder: per (128-token tile, 128-vocab tile) compute logits via
//      bf16 mfma_f32_16x16x32 and reduce to per-token (max,sumexp) chunk stats.
//      grid = (8, NV2). block 256 = 4 waves, each wave owns 64x64 output.
__global__ __launch_bounds__(256) void dec_mfma_k(const unsigned short* __restrict__ Xb,
                                                  const unsigned short* __restrict__ Wb,
                                                  float* __restrict__ cm,
                                                  float* __restrict__ cs) {
    // LDS tiles: 128 rows x 32 k, row stride 40 elems (80 B) to spread banks.
    __shared__ alignas(16) unsigned short Xs[128 * 40];
    __shared__ alignas(16) unsigned short Ws[128 * 40];
    __shared__ float redM[2][128];
    __shared__ float redS[2][128];
    int tid = threadIdx.x;
    int bt = blockIdx.x << 7;   // padded token base (0..1023)
    int bn = blockIdx.y << 7;   // vocab base
    // staging: each thread loads rows (sr, sr+64), 8 bf16 (16 B) per operand per K-step
    int sr = tid >> 2;
    int sk = (tid & 3) << 3;
    int tt0 = bt + sr;       if (tt0 > 1019) tt0 = 1019;
    int tt1 = bt + sr + 64;  if (tt1 > 1019) tt1 = 1019;
    int a0 = (tt0 / 255) * 256 + (tt0 % 255);
    int a1 = (tt1 / 255) * 256 + (tt1 % 255);
    int w0 = bn + sr;        if (w0 > 50256) w0 = 50256;
    int w1 = bn + sr + 64;   if (w1 > 50256) w1 = 50256;
    const unsigned short* Xp0 = Xb + (size_t)a0 * 1024 + sk;
    const unsigned short* Xp1 = Xb + (size_t)a1 * 1024 + sk;
    const unsigned short* Wp0 = Wb + (size_t)w0 * 1024 + sk;
    const unsigned short* Wp1 = Wb + (size_t)w1 * 1024 + sk;
    unsigned short* xs0 = &Xs[sr * 40 + sk];
    unsigned short* xs1 = &Xs[(sr + 64) * 40 + sk];
    unsigned short* ws0 = &Ws[sr * 40 + sk];
    unsigned short* ws1 = &Ws[(sr + 64) * 40 + sk];
    // wave tiling: 2x2 waves of 64x64
    int lane = tid & 63;
    int wv = tid >> 6;
    int wm = (wv >> 1) << 6;
    int wn = (wv & 1) << 6;
    int fr = lane & 15;          // A: token row / B: vocab col within fragment
    int kg = (lane >> 4) << 3;   // k offset 0,8,16,24
    f32x4 acc[4][4] = {};
    for (int k0 = 0; k0 < 1024; k0 += 32) {
        *(float4*)xs0 = *(const float4*)(Xp0 + k0);
        *(float4*)xs1 = *(const float4*)(Xp1 + k0);
        *(float4*)ws0 = *(const float4*)(Wp0 + k0);
        *(float4*)ws1 = *(const float4*)(Wp1 + k0);
        __syncthreads();
        bf16x8 af[4], bfr[4];
#pragma unroll
        for (int i = 0; i < 4; ++i)
            af[i] = *(const bf16x8*)&Xs[(wm + i * 16 + fr) * 40 + kg];
#pragma unroll
        for (int j = 0; j < 4; ++j)
            bfr[j] = *(const bf16x8*)&Ws[(wn + j * 16 + fr) * 40 + kg];
#pragma unroll
        for (int i = 0; i < 4; ++i)
#pragma unroll
            for (int j = 0; j < 4; ++j)
                acc[i][j] = __builtin_amdgcn_mfma_f32_16x16x32_bf16(af[i], bfr[j], acc[i][j], 0, 0, 0);
        __syncthreads();
    }
    // epilogue: per-token chunk max/sumexp over this block's 128 vocab cols.
    // D layout (measured m89/m91): col = lane&15 (vocab), row = (lane>>4)*4 + reg (token).
#pragma unroll
    for (int i = 0; i < 4; ++i) {
#pragma unroll
        for (int r = 0; r < 4; ++r) {
            float M = -INFINITY;
#pragma unroll
            for (int j = 0; j < 4; ++j) {
                int v = bn + wn + j * 16 + fr;
                float val = (v <= 50256) ? acc[i][j][r] : -INFINITY;
                M = fmaxf(M, val);
            }
#pragma unroll
            for (int m = 1; m < 16; m <<= 1) M = fmaxf(M, __shfl_xor(M, m));
            float S = 0.0f;
#pragma unroll
            for (int j = 0; j < 4; ++j) {
                int v = bn + wn + j * 16 + fr;
                if (v <= 50256) S += __expf(acc[i][j][r] - M);
            }
#pragma unroll
            for (int m = 1; m < 16; m <<= 1) S += __shfl_xor(S, m);
            if (fr == 0) {
                int tl = wm + i * 16 + ((lane >> 4) << 2) + r;
                redM[wn >> 6][tl] = M;
                redS[wn >> 6][tl] = S;
            }
        }
    }
    __syncthreads();
    if (tid < 128) {
        float m0 = redM[0][tid], s0 = redS[0][tid];
        float m1 = redM[1][tid], s1 = redS[1][tid];
        float M = fmaxf(m0, m1), S = 0.0f;
        if (s0 > 0.0f) S += s0 * __expf(m0 - M);
        if (s1 > 0.0f) S += s1 * __expf(m1 - M);
        int t = bt + tid;
        if (t < NTOK) {
            cm[(size_t)t * NV2 + blockIdx.y] = M;
            cs[(size_t)t * NV2 + blockIdx.y] = S;
        }
    }
}

// ---- fp32 fallback decoder: per (64-vocab tile, 64-token tile) logits ->
//      per-token (max, sumexp) chunk stats. grid = (786, 16)
__global__ __launch_bounds__(256) void dec_lse_k(const float* __restrict__ X,
                                                 const float* __restrict__ Wv,
                                                 float* __restrict__ cm,
                                                 float* __restrict__ cs) {
    __shared__ alignas(16) float As[16][64];
    __shared__ alignas(16) float Ws[16][64];
    __shared__ float sm[64][16];
    __shared__ float ssum[64][16];
    int tid = threadIdx.x;
    int bn = blockIdx.x << 6, bt = blockIdx.y << 6;
    int tx = tid & 15, ty = tid >> 4;
    int lrow = tid >> 2, lk4 = (tid & 3) << 2;
    int tt = bt + lrow; if (tt > 1019) tt = 1019;
    int bb = tt / 255;
    int arow = bb * 256 + (tt - bb * 255);
    int wrow = bn + lrow; if (wrow > 50256) wrow = 50256;
    const float* Ap = X + (size_t)arow * 1024 + lk4;
    const float* Wp = Wv + (size_t)wrow * 1024 + lk4;
    float acc[4][4] = {};
    for (int k0 = 0; k0 < 1024; k0 += 16) {
        float4 av = *(const float4*)(Ap + k0);
        float4 wv = *(const float4*)(Wp + k0);
        As[lk4 + 0][lrow] = av.x; As[lk4 + 1][lrow] = av.y;
        As[lk4 + 2][lrow] = av.z; As[lk4 + 3][lrow] = av.w;
        Ws[lk4 + 0][lrow] = wv.x; Ws[lk4 + 1][lrow] = wv.y;
        Ws[lk4 + 2][lrow] = wv.z; Ws[lk4 + 3][lrow] = wv.w;
        __syncthreads();
#pragma unroll
        for (int k = 0; k < 16; ++k) {
            float4 a4 = *(const float4*)&As[k][ty << 2];
            float4 b4 = *(const float4*)&Ws[k][tx << 2];
            float a[4] = {a4.x, a4.y, a4.z, a4.w};
            float b[4] = {b4.x, b4.y, b4.z, b4.w};
#pragma unroll
            for (int ii = 0; ii < 4; ++ii)
#pragma unroll
                for (int jj = 0; jj < 4; ++jj) acc[ii][jj] += a[ii] * b[jj];
        }
        __syncthreads();
    }
#pragma unroll
    for (int ii = 0; ii < 4; ++ii) {
        float M = -INFINITY, S = 0.0f;
#pragma unroll
        for (int jj = 0; jj < 4; ++jj) {
            int v = bn + (tx << 2) + jj;
            if (v < 50257) {
                float l = acc[ii][jj];
                if (l > M) { S = S * __expf(M - l) + 1.0f; M = l; }
                else S += __expf(l - M);
            }
        }
        sm[(ty << 2) + ii][tx] = M;
        ssum[(ty << 2) + ii][tx] = S;
    }
    __syncthreads();
    if (tid < 64) {
        float M = -INFINITY, S = 0.0f;
        for (int c = 0; c < 16; ++c) {
            float m2 = sm[tid][c], s2 = ssum[tid][c];
            if (s2 > 0.0f) {
                if (m2 > M) { S = S * __expf(M - m2) + s2; M = m2; }
                else S += s2 * __expf(m2 - M);
            }
        }
        int t = bt + tid;
        if (t < NTOK) {
            cm[(size_t)t * NVT + blockIdx.x] = M;
            cs[(size_t)t * NVT + blockIdx.x] = S;
        }
    }
}

// ---- exact label logit per CE token. grid = 1020
__global__ __launch_bounds__(256) void label_logit_k(const float* __restrict__ X,
                                                     const float* __restrict__ Wv,
                                                     const int* __restrict__ inp,
                                                     float* __restrict__ ll) {
    __shared__ float red[256];
    int t = blockIdx.x, tid = threadIdx.x;
    int b = t / 255, s = t - b * 255;
    int lbl = inp[b * 256 + s + 1];
    int row = b * 256 + s;
    float4 xv = *(const float4*)(X + (size_t)row * 1024 + tid * 4);
    float4 wv = *(const float4*)(Wv + (size_t)lbl * 1024 + tid * 4);
    float p = xv.x * wv.x + xv.y * wv.y + xv.z * wv.z + xv.w * wv.w;
    float tot = block_sum(p, red);
    if (tid == 0) ll[t] = tot;
}

// ---- combine chunk stats -> per-token (lse - label). grid = 1020
__global__ __launch_bounds__(256) void fin_a_k(const float* __restrict__ cm,
                                               const float* __restrict__ cs,
                                               const float* __restrict__ ll,
                                               float* __restrict__ cep, int nvt) {
    __shared__ float rm[256], rs[256];
    int t = blockIdx.x, tid = threadIdx.x;
    float M = -INFINITY, S = 0.0f;
    for (int c = tid; c < nvt; c += 256) {
        float m2 = cm[(size_t)t * nvt + c], s2 = cs[(size_t)t * nvt + c];
        if (s2 > 0.0f) {
            if (m2 > M) { S = S * __expf(M - m2) + s2; M = m2; }
            else S += s2 * __expf(m2 - M);
        }
    }
    rm[tid] = M; rs[tid] = S;
    __syncthreads();
    for (int s = 128; s; s >>= 1) {
        if (tid < s) {
            float m2 = rm[tid + s], s2 = rs[tid + s];
            if (s2 > 0.0f) {
                if (m2 > rm[tid]) { rs[tid] = rs[tid] * __expf(rm[tid] - m2) + s2; rm[tid] = m2; }
                else rs[tid] += s2 * __expf(m2 - rm[tid]);
            }
        }
        __syncthreads();
    }
    if (tid == 0) cep[t] = (rm[0] + logf(rs[0])) - ll[t];
}

// ---- final loss: mean(cep) + imp -> out[0]
__global__ __launch_bounds__(256) void fin_b_k(const float* __restrict__ cep,
                                               const float* __restrict__ impp,
                                               float* __restrict__ out) {
    __shared__ float red[256];
    int tid = threadIdx.x;
    float p = 0;
    for (int i = tid; i < NTOK; i += 256) p += cep[i];
    float tot = block_sum(p, red);
    if (tid == 0) out[0] = tot * (1.0f / NTOK) + impp[0];
}

extern "C" void kernel_launch(void* const* d_in, const int* in_sizes, int n_in,
                              void* d_out, int out_size, void* d_ws, size_t ws_size,
                              hipStream_t stream) {
    const int* inputs = (const int*)d_in[0];
    const float* responses = (const float*)d_in[1];
    const float* noise = (const float*)d_in[2];
    const float* emb = (const float*)d_in[3];
    const float* locWqkv = (const float*)d_in[4];
    const float* locbqkv = (const float*)d_in[5];
    const float* locWo = (const float*)d_in[6];
    const float* locbo = (const float*)d_in[7];
    const float* locg1 = (const float*)d_in[8];
    const float* locb1 = (const float*)d_in[9];
    const float* locW1 = (const float*)d_in[10];
    const float* locbb1 = (const float*)d_in[11];
    const float* locW2 = (const float*)d_in[12];
    const float* locbb2 = (const float*)d_in[13];
    const float* locg2 = (const float*)d_in[14];
    const float* locb2 = (const float*)d_in[15];
    const float* eWqkv = (const float*)d_in[16];
    const float* ebqkv = (const float*)d_in[17];
    const float* eWo = (const float*)d_in[18];
    const float* ebo = (const float*)d_in[19];
    const float* eg1 = (const float*)d_in[20];
    const float* eb1 = (const float*)d_in[21];
    const float* eW1 = (const float*)d_in[22];
    const float* ebb1 = (const float*)d_in[23];
    const float* eW2 = (const float*)d_in[24];
    const float* ebb2 = (const float*)d_in[25];
    const float* eg2 = (const float*)d_in[26];
    const float* eb2 = (const float*)d_in[27];
    const float* gatew = (const float*)d_in[28];
    const float* gateb = (const float*)d_in[29];
    const float* decw = (const float*)d_in[30];
    float* out = (float*)d_out;

    float* w = (float*)d_ws;
    size_t off = 0;
    auto alloc = [&](size_t n) { float* p = w + off; off += (n + 63) & ~(size_t)63; return p; };
    float* xA = alloc(1048576);
    float* xB = alloc(1048576);
    float* attnO = alloc(1048576);
    float* proj = alloc(1048576);
    float* qkv = alloc(3145728);   // also reused for decoder stats later
    float* shR = alloc(4194304);   // scores | ffn hidden (disjoint phases)
    float* xlast = alloc(4096);
    float* attnlast = alloc(4096);
    float* projlast = alloc(4096);
    float* x1last = alloc(4096);
    float* hlast = alloc(16384);
    float* flast = alloc(4096);
    float* ctxlast = alloc(4096);
    float* weightsF = alloc(8192);
    float* jwp = alloc(64);
    float* impp = alloc(64);
    float* cm = qkv;                     // 1020*786 (fallback) / 1020*393 (mfma)
    float* cs = qkv + 801720;            // 1020*786
    float* ll = qkv + 1603440;           // 1020
    float* cep = qkv + 1604480;          // 1020
    size_t base_need = off * sizeof(float);
    // bf16 decoder buffers (large): only used if workspace allows
    float* Xbf = alloc(524288);          // 1024*1024 bf16
    float* Wbf = alloc(25731584);        // 50257*1024 bf16
    size_t mfma_need = off * sizeof(float);
    bool use_mfma = (ws_size >= mfma_need) && (ws_size >= base_need);

    // ---- loc layer (only last position needed downstream)
    embed_k<<<1024, 256, 0, stream>>>(inputs, emb, xA);
    gemm_nt_k<<<dim3(48, 16), 256, 0, stream>>>(xA, locWqkv, locbqkv, qkv, 3072, 1024, 0);
    copy_last_k<<<4, 256, 0, stream>>>(xA, xlast);
    attn_last_k<<<64, 256, 0, stream>>>(qkv, attnlast);
    rowgemm_k<<<256, 256, 0, stream>>>(attnlast, locWo, locbo, projlast, 1024, 1024, 0);
    add_ln_k<<<4, 256, 0, stream>>>(projlast, xlast, locg1, locb1, x1last, 1.0f);
    rowgemm_k<<<1024, 256, 0, stream>>>(x1last, locW1, locbb1, hlast, 4096, 1024, 1);
    rowgemm_k<<<256, 256, 0, stream>>>(hlast, locW2, locbb2, flast, 1024, 4096, 0);
    add_ln_k<<<4, 256, 0, stream>>>(flast, x1last, locg2, locb2, ctxlast, 32.0f);
    rowgemm_k<<<500, 256, 0, stream>>>(ctxlast, gatew, gateb, weightsF, 2000, 1024, 0);
    gate_stats_k<<<1, 256, 0, stream>>>(weightsF, noise, jwp, impp, out);
    qh_k<<<1024, 256, 0, stream>>>(responses, jwp, xA);

    // convert decoder weights to bf16 (independent of everything above)
    if (use_mfma)
        cvt_bf16_k<<<2048, 256, 0, stream>>>(decw, (unsigned short*)Wbf, 12865792);

    // ---- 2 encoder layers (full sequence)
    for (int l = 0; l < 2; ++l) {
        const float* Wq = eWqkv + (size_t)l * 3145728;
        const float* bq = ebqkv + (size_t)l * 3072;
        const float* Wo = eWo + (size_t)l * 1048576;
        const float* bo = ebo + (size_t)l * 1024;
        const float* g1 = eg1 + (size_t)l * 1024;
        const float* b1 = eb1 + (size_t)l * 1024;
        const float* W1 = eW1 + (size_t)l * 4194304;
        const float* bb1 = ebb1 + (size_t)l * 4096;
        const float* W2 = eW2 + (size_t)l * 4194304;
        const float* bb2 = ebb2 + (size_t)l * 4096;
        const float* g2 = eg2 + (size_t)l * 1024;
        const float* b2 = eb2 + (size_t)l * 1024;
        gemm_nt_k<<<dim3(48, 16), 256, 0, stream>>>(xA, Wq, bq, qkv, 3072, 1024, 0);
        attn_scores_k<<<512, 256, 0, stream>>>(qkv, shR);
        attn_av_k<<<512, 256, 0, stream>>>(qkv, shR, attnO);
        gemm_nt_k<<<dim3(16, 16), 256, 0, stream>>>(attnO, Wo, bo, proj, 1024, 1024, 0);
        add_ln_k<<<1024, 256, 0, stream>>>(proj, xA, g1, b1, xB, 1.0f);
        gemm_nt_k<<<dim3(64, 16), 256, 0, stream>>>(xB, W1, bb1, shR, 4096, 1024, 1);
        gemm_nt_k<<<dim3(16, 16), 256, 0, stream>>>(shR, W2, bb2, proj, 1024, 4096, 0);
        add_ln_k<<<1024, 256, 0, stream>>>(proj, xB, g2, b2, xA, 1.0f);
    }

    // ---- decoder CE (streaming logsumexp, no logits materialization)
    if (use_mfma) {
        cvt_bf16_k<<<512, 256, 0, stream>>>(xA, (unsigned short*)Xbf, 262144);
        dec_mfma_k<<<dim3(8, NV2), 256, 0, stream>>>((const unsigned short*)Xbf,
                                                     (const unsigned short*)Wbf, cm, cs);
        label_logit_k<<<NTOK, 256, 0, stream>>>(xA, decw, inputs, ll);
        fin_a_k<<<NTOK, 256, 0, stream>>>(cm, cs, ll, cep, NV2);
    } else {
        dec_lse_k<<<dim3(NVT, 16), 256, 0, stream>>>(xA, decw, cm, cs);
        label_logit_k<<<NTOK, 256, 0, stream>>>(xA, decw, inputs, ll);
        fin_a_k<<<NTOK, 256, 0, stream>>>(cm, cs, ll, cep, NVT);
    }
    fin_b_k<<<1, 256, 0, stream>>>(cep, impp, out);
}

// Round 2
// 1803.464 us; speedup vs baseline: 1.2831x; 1.2831x over previous
//
#include <hip/hip_runtime.h>
#include <hip/hip_bf16.h>

// Sizes (compile-time constants from the reference)
// V=50257, D=1024, H=16, FF=4096, L=2, N=2000, K=20, B=4, S=256
#define NVT 786   // ceil(50257/64) vocab tiles (fp32 fallback path)
#define NV2 393   // ceil(50257/128) vocab tiles (MFMA path)
#define NTOK 1020 // B*(S-1) CE tokens

typedef __attribute__((ext_vector_type(8))) __bf16 bf16x8;
typedef __attribute__((ext_vector_type(4))) float f32x4;

__device__ __forceinline__ float block_sum(float v, float* red) {
    int tid = threadIdx.x;
    red[tid] = v;
    __syncthreads();
    for (int s = 128; s > 0; s >>= 1) {
        if (tid < s) red[tid] += red[tid + s];
        __syncthreads();
    }
    float r = red[0];
    __syncthreads();
    return r;
}

__device__ __forceinline__ unsigned short f2bf(float f) {
    union { float f; unsigned int u; } v; v.f = f;
    unsigned int r = v.u + 0x7fffu + ((v.u >> 16) & 1u);
    return (unsigned short)(r >> 16);
}

// ---- fp32 -> bf16 (RNE), vectorized, grid-stride over float4s
__global__ __launch_bounds__(256) void cvt_bf16_k(const float* __restrict__ in,
                                                  unsigned short* __restrict__ out,
                                                  int n4) {
    int i = blockIdx.x * 256 + threadIdx.x;
    int stride = gridDim.x * 256;
    for (; i < n4; i += stride) {
        float4 v = ((const float4*)in)[i];
        ushort4 o;
        o.x = f2bf(v.x); o.y = f2bf(v.y); o.z = f2bf(v.z); o.w = f2bf(v.w);
        ((ushort4*)out)[i] = o;
    }
}

// ---- embedding gather: x[row,:] = emb[inputs[row],:]  (1024 rows of 1024)
__global__ __launch_bounds__(256) void embed_k(const int* __restrict__ inp,
                                               const float* __restrict__ emb,
                                               float* __restrict__ x) {
    int row = blockIdx.x;
    int tok = inp[row];
    int d = threadIdx.x * 4;
    float4 v = *(const float4*)(emb + (size_t)tok * 1024 + d);
    *(float4*)(x + (size_t)row * 1024 + d) = v;
}

// ---- copy last seq position per batch: xl[b,:] = x[b*256+255,:]
__global__ __launch_bounds__(256) void copy_last_k(const float* __restrict__ x,
                                                   float* __restrict__ xl) {
    int b = blockIdx.x;
    int d = threadIdx.x * 4;
    float4 v = *(const float4*)(x + (size_t)(b * 256 + 255) * 1024 + d);
    *(float4*)(xl + (size_t)b * 1024 + d) = v;
}

// ---- generic NT gemm (fp32 SIMT): C[M,N] = A[M,K] * W[N,K]^T + bias, opt relu
// N is the output ROW STRIDE; columns covered = gridDim.x*64 (may be < N).
__global__ __launch_bounds__(256) void gemm_nt_k(const float* __restrict__ A,
                                                 const float* __restrict__ W,
                                                 const float* __restrict__ bias,
                                                 float* __restrict__ C,
                                                 int N, int K, int relu) {
    __shared__ alignas(16) float As[16][64];
    __shared__ alignas(16) float Ws[16][64];
    int tid = threadIdx.x;
    int bm = blockIdx.y << 6, bn = blockIdx.x << 6;
    int tx = tid & 15, ty = tid >> 4;
    int lrow = tid >> 2, lk4 = (tid & 3) << 2;
    const float* Ap = A + (size_t)(bm + lrow) * K + lk4;
    const float* Wp = W + (size_t)(bn + lrow) * K + lk4;
    float acc[4][4] = {};
    for (int k0 = 0; k0 < K; k0 += 16) {
        float4 av = *(const float4*)(Ap + k0);
        float4 wv = *(const float4*)(Wp + k0);
        As[lk4 + 0][lrow] = av.x; As[lk4 + 1][lrow] = av.y;
        As[lk4 + 2][lrow] = av.z; As[lk4 + 3][lrow] = av.w;
        Ws[lk4 + 0][lrow] = wv.x; Ws[lk4 + 1][lrow] = wv.y;
        Ws[lk4 + 2][lrow] = wv.z; Ws[lk4 + 3][lrow] = wv.w;
        __syncthreads();
#pragma unroll
        for (int k = 0; k < 16; ++k) {
            float4 a4 = *(const float4*)&As[k][ty << 2];
            float4 b4 = *(const float4*)&Ws[k][tx << 2];
            float a[4] = {a4.x, a4.y, a4.z, a4.w};
            float b[4] = {b4.x, b4.y, b4.z, b4.w};
#pragma unroll
            for (int i = 0; i < 4; ++i)
#pragma unroll
                for (int j = 0; j < 4; ++j) acc[i][j] += a[i] * b[j];
        }
        __syncthreads();
    }
#pragma unroll
    for (int i = 0; i < 4; ++i) {
        int m = bm + (ty << 2) + i;
#pragma unroll
        for (int j = 0; j < 4; ++j) {
            int n = bn + (tx << 2) + j;
            float v = acc[i][j] + bias[n];
            if (relu) v = fmaxf(v, 0.0f);
            C[(size_t)m * N + n] = v;
        }
    }
}

// ---- bf16 MFMA NT gemm: C[M,N] = A[M,K] * Wb[N,K]^T + bias, opt relu.
// A fp32 (converted to bf16 inline during staging), Wb pre-converted bf16.
// Tile 128x128, BK=32, block 256 = 4 waves (2x2 of 64x64). M,N mult of 128, K mult of 32.
__global__ __launch_bounds__(256) void gemm_mfma_k(const float* __restrict__ A,
                                                   const unsigned short* __restrict__ Wb,
                                                   const float* __restrict__ bias,
                                                   float* __restrict__ C,
                                                   int N, int K, int relu) {
    __shared__ alignas(16) unsigned short Xs[128 * 40];
    __shared__ alignas(16) unsigned short Ws[128 * 40];
    int tid = threadIdx.x;
    int bn = blockIdx.x << 7;
    int bm = blockIdx.y << 7;
    int sr = tid >> 2;
    int sk = (tid & 3) << 3;
    const float* Ap0 = A + (size_t)(bm + sr) * K + sk;
    const float* Ap1 = A + (size_t)(bm + sr + 64) * K + sk;
    const unsigned short* Wp0 = Wb + (size_t)(bn + sr) * K + sk;
    const unsigned short* Wp1 = Wb + (size_t)(bn + sr + 64) * K + sk;
    unsigned short* xs0 = &Xs[sr * 40 + sk];
    unsigned short* xs1 = &Xs[(sr + 64) * 40 + sk];
    unsigned short* ws0 = &Ws[sr * 40 + sk];
    unsigned short* ws1 = &Ws[(sr + 64) * 40 + sk];
    int lane = tid & 63;
    int wv = tid >> 6;
    int wm = (wv >> 1) << 6;
    int wn = (wv & 1) << 6;
    int fr = lane & 15;
    int kg = (lane >> 4) << 3;
    f32x4 acc[4][4] = {};
    for (int k0 = 0; k0 < K; k0 += 32) {
        float4 al0 = *(const float4*)(Ap0 + k0);
        float4 ah0 = *(const float4*)(Ap0 + k0 + 4);
        float4 al1 = *(const float4*)(Ap1 + k0);
        float4 ah1 = *(const float4*)(Ap1 + k0 + 4);
        float4 w0 = *(const float4*)(Wp0 + k0);
        float4 w1 = *(const float4*)(Wp1 + k0);
        ushort4 p0 = {f2bf(al0.x), f2bf(al0.y), f2bf(al0.z), f2bf(al0.w)};
        ushort4 p1 = {f2bf(ah0.x), f2bf(ah0.y), f2bf(ah0.z), f2bf(ah0.w)};
        ushort4 p2 = {f2bf(al1.x), f2bf(al1.y), f2bf(al1.z), f2bf(al1.w)};
        ushort4 p3 = {f2bf(ah1.x), f2bf(ah1.y), f2bf(ah1.z), f2bf(ah1.w)};
        *(ushort4*)xs0 = p0; *(ushort4*)(xs0 + 4) = p1;
        *(ushort4*)xs1 = p2; *(ushort4*)(xs1 + 4) = p3;
        *(float4*)ws0 = w0;
        *(float4*)ws1 = w1;
        __syncthreads();
        bf16x8 af[4], bfr[4];
#pragma unroll
        for (int i = 0; i < 4; ++i)
            af[i] = *(const bf16x8*)&Xs[(wm + i * 16 + fr) * 40 + kg];
#pragma unroll
        for (int j = 0; j < 4; ++j)
            bfr[j] = *(const bf16x8*)&Ws[(wn + j * 16 + fr) * 40 + kg];
#pragma unroll
        for (int i = 0; i < 4; ++i)
#pragma unroll
            for (int j = 0; j < 4; ++j)
                acc[i][j] = __builtin_amdgcn_mfma_f32_16x16x32_bf16(af[i], bfr[j], acc[i][j], 0, 0, 0);
        __syncthreads();
    }
    // D layout: col = lane&15, row = (lane>>4)*4 + reg (verified via dec_mfma_k)
    int rb = bm + wm + ((lane >> 4) << 2);
    int cb = bn + wn + fr;
    float bv[4];
#pragma unroll
    for (int j = 0; j < 4; ++j) bv[j] = bias[cb + j * 16];
#pragma unroll
    for (int i = 0; i < 4; ++i)
#pragma unroll
        for (int j = 0; j < 4; ++j)
#pragma unroll
            for (int r = 0; r < 4; ++r) {
                float v = acc[i][j][r] + bv[j];
                if (relu) v = fmaxf(v, 0.0f);
                C[(size_t)(rb + i * 16 + r) * N + cb + j * 16] = v;
            }
}

// ---- loc-layer attention, query = last position only (Q from qlast). grid = B*H = 64.
__global__ __launch_bounds__(256) void attn_last_k(const float* __restrict__ qkv,
                                                   const float* __restrict__ qlast,
                                                   float* __restrict__ out) {
    int b = blockIdx.x >> 4, h = blockIdx.x & 15;
    int tid = threadIdx.x;
    __shared__ float qs[64];
    __shared__ float sc[256];
    __shared__ float red[256];
    if (tid < 64) qs[tid] = qlast[(size_t)b * 1024 + h * 64 + tid];
    __syncthreads();
    const float* kp = qkv + (size_t)(b * 256 + tid) * 3072 + 1024 + h * 64;
    float s = 0;
    for (int d = 0; d < 64; ++d) s += qs[d] * kp[d];
    s *= 0.125f;
    red[tid] = s;
    __syncthreads();
    for (int st = 128; st; st >>= 1) { if (tid < st) red[tid] = fmaxf(red[tid], red[tid + st]); __syncthreads(); }
    float mx = red[0];
    __syncthreads();
    float e = __expf(s - mx);
    red[tid] = e;
    __syncthreads();
    for (int st = 128; st; st >>= 1) { if (tid < st) red[tid] += red[tid + st]; __syncthreads(); }
    float inv = 1.0f / red[0];
    __syncthreads();
    sc[tid] = e * inv;
    __syncthreads();
    if (tid < 64) {
        const float* vp = qkv + 2048 + h * 64 + tid;
        float o = 0;
        for (int j = 0; j < 256; ++j) o += sc[j] * vp[(size_t)(b * 256 + j) * 3072];
        out[(size_t)b * 1024 + h * 64 + tid] = o;
    }
}

// ---- small-M (M=4) gemm: out[4,N] = A[4,K] * W[N,K]^T + bias; one wave per n
__global__ __launch_bounds__(256) void rowgemm_k(const float* __restrict__ A,
                                                 const float* __restrict__ W,
                                                 const float* __restrict__ bias,
                                                 float* __restrict__ out,
                                                 int N, int K, int relu) {
    int n = blockIdx.x * 4 + (threadIdx.x >> 6);
    if (n >= N) return;
    int lane = threadIdx.x & 63;
    const float* Wp = W + (size_t)n * K;
    float a0 = 0, a1 = 0, a2 = 0, a3 = 0;
    for (int k = lane * 4; k < K; k += 256) {
        float4 wv = *(const float4*)(Wp + k);
        float4 x0 = *(const float4*)(A + k);
        float4 x1 = *(const float4*)(A + K + k);
        float4 x2 = *(const float4*)(A + 2 * K + k);
        float4 x3 = *(const float4*)(A + 3 * K + k);
        a0 += wv.x * x0.x + wv.y * x0.y + wv.z * x0.z + wv.w * x0.w;
        a1 += wv.x * x1.x + wv.y * x1.y + wv.z * x1.z + wv.w * x1.w;
        a2 += wv.x * x2.x + wv.y * x2.y + wv.z * x2.z + wv.w * x2.w;
        a3 += wv.x * x3.x + wv.y * x3.y + wv.z * x3.z + wv.w * x3.w;
    }
    for (int o = 32; o; o >>= 1) {
        a0 += __shfl_down(a0, o); a1 += __shfl_down(a1, o);
        a2 += __shfl_down(a2, o); a3 += __shfl_down(a3, o);
    }
    if (lane == 0) {
        float bs = bias[n];
        float v0 = a0 + bs, v1 = a1 + bs, v2 = a2 + bs, v3 = a3 + bs;
        if (relu) { v0 = fmaxf(v0, 0.f); v1 = fmaxf(v1, 0.f); v2 = fmaxf(v2, 0.f); v3 = fmaxf(v3, 0.f); }
        out[n] = v0; out[N + n] = v1; out[2 * N + n] = v2; out[3 * N + n] = v3;
    }
}

// ---- out[row,:] = LN(a[row,:] + r[row,:]) * g + b, then *scale. D=1024. grid=rows
__global__ __launch_bounds__(256) void add_ln_k(const float* __restrict__ a,
                                                const float* __restrict__ r,
                                                const float* __restrict__ g,
                                                const float* __restrict__ bb,
                                                float* __restrict__ out, float scale) {
    __shared__ float red[256];
    int tid = threadIdx.x;
    size_t base = (size_t)blockIdx.x * 1024 + tid * 4;
    float4 av = *(const float4*)(a + base);
    float4 rv = *(const float4*)(r + base);
    float v0 = av.x + rv.x, v1 = av.y + rv.y, v2 = av.z + rv.z, v3 = av.w + rv.w;
    float mean = block_sum(v0 + v1 + v2 + v3, red) * (1.0f / 1024.0f);
    float d0 = v0 - mean, d1 = v1 - mean, d2 = v2 - mean, d3 = v3 - mean;
    float var = block_sum(d0 * d0 + d1 * d1 + d2 * d2 + d3 * d3, red) * (1.0f / 1024.0f);
    float rstd = rsqrtf(var + 1e-5f);
    float4 gv = *(const float4*)(g + tid * 4);
    float4 bv = *(const float4*)(bb + tid * 4);
    float4 o;
    o.x = (d0 * rstd * gv.x + bv.x) * scale;
    o.y = (d1 * rstd * gv.y + bv.y) * scale;
    o.z = (d2 * rstd * gv.z + bv.z) * scale;
    o.w = (d3 * rstd * gv.w + bv.w) * scale;
    *(float4*)(out + base) = o;
}

// ---- gate stats: fm, total, imp, top-20 -> jw; also writes weights to out[1..8000]
__global__ __launch_bounds__(256) void gate_stats_k(const float* __restrict__ wf,
                                                    const float* __restrict__ noise,
                                                    float* __restrict__ jw,
                                                    float* __restrict__ impp,
                                                    float* __restrict__ out) {
    int tid = threadIdx.x;
    __shared__ float fm[2000];
    __shared__ float tot[2000];
    __shared__ float red[256];
    __shared__ int redi[256];
    __shared__ float topv[20];
    for (int n = tid; n < 2000; n += 256)
        fm[n] = 0.25f * (wf[n] + wf[2000 + n] + wf[4000 + n] + wf[6000 + n]);
    __syncthreads();
    float p = 0;
    for (int n = tid; n < 2000; n += 256) p += fm[n];
    float mean_fm = block_sum(p, red) * (1.0f / 2000.0f);
    p = 0;
    for (int n = tid; n < 2000; n += 256) { float d = fm[n] - mean_fm; p += d * d; }
    float std_fm = sqrtf(block_sum(p, red) * (1.0f / 1999.0f));
    for (int n = tid; n < 2000; n += 256) tot[n] = fm[n] + noise[n] * std_fm;
    __syncthreads();
    p = 0;
    for (int n = tid; n < 2000; n += 256) p += tot[n];
    float mean_t = block_sum(p, red) * (1.0f / 2000.0f);
    p = 0;
    for (int n = tid; n < 2000; n += 256) { float d = tot[n] - mean_t; p += d * d; }
    float var_t = block_sum(p, red) * (1.0f / 1999.0f);
    float imp = 0.1f * var_t / (mean_t * mean_t);
    for (int n = tid; n < 2000; n += 256) fm[n] = tot[n];
    __syncthreads();
    for (int it = 0; it < 20; ++it) {
        float bv = -INFINITY; int bi = 0x7fffffff;
        for (int n = tid; n < 2000; n += 256) {
            float v = fm[n];
            if (v > bv || (v == bv && n < bi)) { bv = v; bi = n; }
        }
        red[tid] = bv; redi[tid] = bi;
        __syncthreads();
        for (int s = 128; s; s >>= 1) {
            if (tid < s) {
                float v2 = red[tid + s]; int i2 = redi[tid + s];
                if (v2 > red[tid] || (v2 == red[tid] && i2 < redi[tid])) { red[tid] = v2; redi[tid] = i2; }
            }
            __syncthreads();
        }
        if (tid == 0) { topv[it] = red[0]; fm[redi[0]] = -INFINITY; }
        __syncthreads();
    }
    if (tid == 0) {
        float mx = topv[0];
        float s = 0;
        for (int i = 0; i < 20; ++i) s += __expf(topv[i] - mx);
        float inv = 1.0f / s;
        for (int i = 0; i < 20; ++i) jw[i] = __expf(topv[i] - mx) * inv;
        impp[0] = imp;
    }
    for (int idx = tid; idx < 8000; idx += 256) out[1 + idx] = wf[idx];
}

// ---- query_hidden = sum_i jw[i] * responses[i]
__global__ __launch_bounds__(256) void qh_k(const float* __restrict__ resp,
                                            const float* __restrict__ jw,
                                            float* __restrict__ x) {
    __shared__ float jws[20];
    int tid = threadIdx.x;
    if (tid < 20) jws[tid] = jw[tid];
    __syncthreads();
    size_t e0 = ((size_t)blockIdx.x * 256 + tid) * 4;
    float a0 = 0, a1 = 0, a2 = 0, a3 = 0;
    for (int i = 0; i < 20; ++i) {
        float4 r = *(const float4*)(resp + (size_t)i * 1048576 + e0);
        float w = jws[i];
        a0 += w * r.x; a1 += w * r.y; a2 += w * r.z; a3 += w * r.w;
    }
    float4 o = {a0, a1, a2, a3};
    *(float4*)(x + e0) = o;
}

// ---- full attention scores+softmax per (b,h,32-row tile). grid = 4*16*8 = 512
__global__ __launch_bounds__(256) void attn_scores_k(const float* __restrict__ qkv,
                                                     float* __restrict__ aw) {
    int bx = blockIdx.x;
    int it = bx & 7, h = (bx >> 3) & 15, b = bx >> 7;
    int tid = threadIdx.x;
    __shared__ float Qs[32][64];
    __shared__ float Ks[64][64];
    __shared__ float Ss[32][256];
    int i0 = it * 32;
    for (int r = 0; r < 8; ++r) {
        int e = tid + 256 * r;
        int i = e >> 6, d = e & 63;
        Qs[i][d] = qkv[(size_t)(b * 256 + i0 + i) * 3072 + h * 64 + d];
    }
    int i = tid >> 3, jg = tid & 7;
    for (int jt = 0; jt < 4; ++jt) {
        __syncthreads();
        for (int r = 0; r < 16; ++r) {
            int e = tid + 256 * r;
            int j = e >> 6, d = e & 63;
            Ks[j][d] = qkv[(size_t)(b * 256 + jt * 64 + j) * 3072 + 1024 + h * 64 + d];
        }
        __syncthreads();
        for (int jj = 0; jj < 8; ++jj) {
            int jl = jg * 8 + jj;
            float s = 0;
            for (int d = 0; d < 64; ++d) s += Qs[i][d] * Ks[jl][d];
            Ss[i][jt * 64 + jl] = s * 0.125f;
        }
    }
    float m = -INFINITY;
    for (int c = jg; c < 256; c += 8) m = fmaxf(m, Ss[i][c]);
    for (int o = 4; o; o >>= 1) m = fmaxf(m, __shfl_down(m, o, 8));
    m = __shfl(m, 0, 8);
    float sum = 0;
    for (int c = jg; c < 256; c += 8) { float e = __expf(Ss[i][c] - m); Ss[i][c] = e; sum += e; }
    for (int o = 4; o; o >>= 1) sum += __shfl_down(sum, o, 8);
    sum = __shfl(sum, 0, 8);
    float inv = 1.0f / sum;
    size_t base = ((size_t)(b * 16 + h) * 256 + (i0 + i)) * 256;
    for (int c = jg; c < 256; c += 8) aw[base + c] = Ss[i][c] * inv;
}

// ---- attention A@V per (b,h,32-row tile). grid = 512
__global__ __launch_bounds__(256) void attn_av_k(const float* __restrict__ qkv,
                                                 const float* __restrict__ aw,
                                                 float* __restrict__ out) {
    int bx = blockIdx.x;
    int it = bx & 7, h = (bx >> 3) & 15, b = bx >> 7;
    int tid = threadIdx.x;
    __shared__ float As[32][256];
    __shared__ float Vs[64][64];
    int i0 = it * 32;
    for (int r = 0; r < 32; ++r) {
        int e = tid + 256 * r;
        int i = e >> 8, c = e & 255;
        As[i][c] = aw[((size_t)(b * 16 + h) * 256 + i0 + i) * 256 + c];
    }
    int i = tid >> 3, dg = tid & 7;
    float acc[8] = {};
    for (int jt = 0; jt < 4; ++jt) {
        __syncthreads();
        for (int r = 0; r < 16; ++r) {
            int e = tid + 256 * r;
            int j = e >> 6, d = e & 63;
            Vs[j][d] = qkv[(size_t)(b * 256 + jt * 64 + j) * 3072 + 2048 + h * 64 + d];
        }
        __syncthreads();
        for (int jl = 0; jl < 64; ++jl) {
            float a = As[i][jt * 64 + jl];
#pragma unroll
            for (int dd = 0; dd < 8; ++dd) acc[dd] += a * Vs[jl][dg * 8 + dd];
        }
    }
    size_t ob = (size_t)(b * 256 + i0 + i) * 1024 + h * 64 + dg * 8;
#pragma unroll
    for (int dd = 0; dd < 8; ++dd) out[ob + dd] = acc[dd];
}

// ---- MFMA decoder: per (128-token tile, 128-vocab tile) compute logits via
//      bf16 mfma_f32_16x16x32 and reduce to per-token (max,sumexp) chunk stats.
__global__ __launch_bounds__(256) void dec_mfma_k(const unsigned short* __restrict__ Xb,
                                                  const unsigned short* __restrict__ Wb,
                                                  float* __restrict__ cm,
                                                  float* __restrict__ cs) {
    __shared__ alignas(16) unsigned short Xs[128 * 40];
    __shared__ alignas(16) unsigned short Ws[128 * 40];
    __shared__ float redM[2][128];
    __shared__ float redS[2][128];
    int tid = threadIdx.x;
    int bt = blockIdx.x << 7;
    int bn = blockIdx.y << 7;
    int sr = tid >> 2;
    int sk = (tid & 3) << 3;
    int tt0 = bt + sr;       if (tt0 > 1019) tt0 = 1019;
    int tt1 = bt + sr + 64;  if (tt1 > 1019) tt1 = 1019;
    int a0 = (tt0 / 255) * 256 + (tt0 % 255);
    int a1 = (tt1 / 255) * 256 + (tt1 % 255);
    int w0 = bn + sr;        if (w0 > 50256) w0 = 50256;
    int w1 = bn + sr + 64;   if (w1 > 50256) w1 = 50256;
    const unsigned short* Xp0 = Xb + (size_t)a0 * 1024 + sk;
    const unsigned short* Xp1 = Xb + (size_t)a1 * 1024 + sk;
    const unsigned short* Wp0 = Wb + (size_t)w0 * 1024 + sk;
    const unsigned short* Wp1 = Wb + (size_t)w1 * 1024 + sk;
    unsigned short* xs0 = &Xs[sr * 40 + sk];
    unsigned short* xs1 = &Xs[(sr + 64) * 40 + sk];
    unsigned short* ws0 = &Ws[sr * 40 + sk];
    unsigned short* ws1 = &Ws[(sr + 64) * 40 + sk];
    int lane = tid & 63;
    int wv = tid >> 6;
    int wm = (wv >> 1) << 6;
    int wn = (wv & 1) << 6;
    int fr = lane & 15;
    int kg = (lane >> 4) << 3;
    f32x4 acc[4][4] = {};
    for (int k0 = 0; k0 < 1024; k0 += 32) {
        *(float4*)xs0 = *(const float4*)(Xp0 + k0);
        *(float4*)xs1 = *(const float4*)(Xp1 + k0);
        *(float4*)ws0 = *(const float4*)(Wp0 + k0);
        *(float4*)ws1 = *(const float4*)(Wp1 + k0);
        __syncthreads();
        bf16x8 af[4], bfr[4];
#pragma unroll
        for (int i = 0; i < 4; ++i)
            af[i] = *(const bf16x8*)&Xs[(wm + i * 16 + fr) * 40 + kg];
#pragma unroll
        for (int j = 0; j < 4; ++j)
            bfr[j] = *(const bf16x8*)&Ws[(wn + j * 16 + fr) * 40 + kg];
#pragma unroll
        for (int i = 0; i < 4; ++i)
#pragma unroll
            for (int j = 0; j < 4; ++j)
                acc[i][j] = __builtin_amdgcn_mfma_f32_16x16x32_bf16(af[i], bfr[j], acc[i][j], 0, 0, 0);
        __syncthreads();
    }
#pragma unroll
    for (int i = 0; i < 4; ++i) {
#pragma unroll
        for (int r = 0; r < 4; ++r) {
            float M = -INFINITY;
#pragma unroll
            for (int j = 0; j < 4; ++j) {
                int v = bn + wn + j * 16 + fr;
                float val = (v <= 50256) ? acc[i][j][r] : -INFINITY;
                M = fmaxf(M, val);
            }
#pragma unroll
            for (int m = 1; m < 16; m <<= 1) M = fmaxf(M, __shfl_xor(M, m));
            float S = 0.0f;
#pragma unroll
            for (int j = 0; j < 4; ++j) {
                int v = bn + wn + j * 16 + fr;
                if (v <= 50256) S += __expf(acc[i][j][r] - M);
            }
#pragma unroll
            for (int m = 1; m < 16; m <<= 1) S += __shfl_xor(S, m);
            if (fr == 0) {
                int tl = wm + i * 16 + ((lane >> 4) << 2) + r;
                redM[wn >> 6][tl] = M;
                redS[wn >> 6][tl] = S;
            }
        }
    }
    __syncthreads();
    if (tid < 128) {
        float m0 = redM[0][tid], s0 = redS[0][tid];
        float m1 = redM[1][tid], s1 = redS[1][tid];
        float M = fmaxf(m0, m1), S = 0.0f;
        if (s0 > 0.0f) S += s0 * __expf(m0 - M);
        if (s1 > 0.0f) S += s1 * __expf(m1 - M);
        int t = bt + tid;
        if (t < NTOK) {
            cm[(size_t)t * NV2 + blockIdx.y] = M;
            cs[(size_t)t * NV2 + blockIdx.y] = S;
        }
    }
}

// ---- fp32 fallback decoder
__global__ __launch_bounds__(256) void dec_lse_k(const float* __restrict__ X,
                                                 const float* __restrict__ Wv,
                                                 float* __restrict__ cm,
                                                 float* __restrict__ cs) {
    __shared__ alignas(16) float As[16][64];
    __shared__ alignas(16) float Ws[16][64];
    __shared__ float sm[64][16];
    __shared__ float ssum[64][16];
    int tid = threadIdx.x;
    int bn = blockIdx.x << 6, bt = blockIdx.y << 6;
    int tx = tid & 15, ty = tid >> 4;
    int lrow = tid >> 2, lk4 = (tid & 3) << 2;
    int tt = bt + lrow; if (tt > 1019) tt = 1019;
    int bb = tt / 255;
    int arow = bb * 256 + (tt - bb * 255);
    int wrow = bn + lrow; if (wrow > 50256) wrow = 50256;
    const float* Ap = X + (size_t)arow * 1024 + lk4;
    const float* Wp = Wv + (size_t)wrow * 1024 + lk4;
    float acc[4][4] = {};
    for (int k0 = 0; k0 < 1024; k0 += 16) {
        float4 av = *(const float4*)(Ap + k0);
        float4 wv = *(const float4*)(Wp + k0);
        As[lk4 + 0][lrow] = av.x; As[lk4 + 1][lrow] = av.y;
        As[lk4 + 2][lrow] = av.z; As[lk4 + 3][lrow] = av.w;
        Ws[lk4 + 0][lrow] = wv.x; Ws[lk4 + 1][lrow] = wv.y;
        Ws[lk4 + 2][lrow] = wv.z; Ws[lk4 + 3][lrow] = wv.w;
        __syncthreads();
#pragma unroll
        for (int k = 0; k < 16; ++k) {
            float4 a4 = *(const float4*)&As[k][ty << 2];
            float4 b4 = *(const float4*)&Ws[k][tx << 2];
            float a[4] = {a4.x, a4.y, a4.z, a4.w};
            float b[4] = {b4.x, b4.y, b4.z, b4.w};
#pragma unroll
            for (int ii = 0; ii < 4; ++ii)
#pragma unroll
                for (int jj = 0; jj < 4; ++jj) acc[ii][jj] += a[ii] * b[jj];
        }
        __syncthreads();
    }
#pragma unroll
    for (int ii = 0; ii < 4; ++ii) {
        float M = -INFINITY, S = 0.0f;
#pragma unroll
        for (int jj = 0; jj < 4; ++jj) {
            int v = bn + (tx << 2) + jj;
            if (v < 50257) {
                float l = acc[ii][jj];
                if (l > M) { S = S * __expf(M - l) + 1.0f; M = l; }
                else S += __expf(l - M);
            }
        }
        sm[(ty << 2) + ii][tx] = M;
        ssum[(ty << 2) + ii][tx] = S;
    }
    __syncthreads();
    if (tid < 64) {
        float M = -INFINITY, S = 0.0f;
        for (int c = 0; c < 16; ++c) {
            float m2 = sm[tid][c], s2 = ssum[tid][c];
            if (s2 > 0.0f) {
                if (m2 > M) { S = S * __expf(M - m2) + s2; M = m2; }
                else S += s2 * __expf(m2 - M);
            }
        }
        int t = bt + tid;
        if (t < NTOK) {
            cm[(size_t)t * NVT + blockIdx.x] = M;
            cs[(size_t)t * NVT + blockIdx.x] = S;
        }
    }
}

// ---- exact label logit per CE token. grid = 1020
__global__ __launch_bounds__(256) void label_logit_k(const float* __restrict__ X,
                                                     const float* __restrict__ Wv,
                                                     const int* __restrict__ inp,
                                                     float* __restrict__ ll) {
    __shared__ float red[256];
    int t = blockIdx.x, tid = threadIdx.x;
    int b = t / 255, s = t - b * 255;
    int lbl = inp[b * 256 + s + 1];
    int row = b * 256 + s;
    float4 xv = *(const float4*)(X + (size_t)row * 1024 + tid * 4);
    float4 wv = *(const float4*)(Wv + (size_t)lbl * 1024 + tid * 4);
    float p = xv.x * wv.x + xv.y * wv.y + xv.z * wv.z + xv.w * wv.w;
    float tot = block_sum(p, red);
    if (tid == 0) ll[t] = tot;
}

// ---- combine chunk stats -> per-token (lse - label). grid = 1020
__global__ __launch_bounds__(256) void fin_a_k(const float* __restrict__ cm,
                                               const float* __restrict__ cs,
                                               const float* __restrict__ ll,
                                               float* __restrict__ cep, int nvt) {
    __shared__ float rm[256], rs[256];
    int t = blockIdx.x, tid = threadIdx.x;
    float M = -INFINITY, S = 0.0f;
    for (int c = tid; c < nvt; c += 256) {
        float m2 = cm[(size_t)t * nvt + c], s2 = cs[(size_t)t * nvt + c];
        if (s2 > 0.0f) {
            if (m2 > M) { S = S * __expf(M - m2) + s2; M = m2; }
            else S += s2 * __expf(m2 - M);
        }
    }
    rm[tid] = M; rs[tid] = S;
    __syncthreads();
    for (int s = 128; s; s >>= 1) {
        if (tid < s) {
            float m2 = rm[tid + s], s2 = rs[tid + s];
            if (s2 > 0.0f) {
                if (m2 > rm[tid]) { rs[tid] = rs[tid] * __expf(rm[tid] - m2) + s2; rm[tid] = m2; }
                else rs[tid] += s2 * __expf(m2 - rm[tid]);
            }
        }
        __syncthreads();
    }
    if (tid == 0) cep[t] = (rm[0] + logf(rs[0])) - ll[t];
}

// ---- final loss: mean(cep) + imp -> out[0]
__global__ __launch_bounds__(256) void fin_b_k(const float* __restrict__ cep,
                                               const float* __restrict__ impp,
                                               float* __restrict__ out) {
    __shared__ float red[256];
    int tid = threadIdx.x;
    float p = 0;
    for (int i = tid; i < NTOK; i += 256) p += cep[i];
    float tot = block_sum(p, red);
    if (tid == 0) out[0] = tot * (1.0f / NTOK) + impp[0];
}

extern "C" void kernel_launch(void* const* d_in, const int* in_sizes, int n_in,
                              void* d_out, int out_size, void* d_ws, size_t ws_size,
                              hipStream_t stream) {
    const int* inputs = (const int*)d_in[0];
    const float* responses = (const float*)d_in[1];
    const float* noise = (const float*)d_in[2];
    const float* emb = (const float*)d_in[3];
    const float* locWqkv = (const float*)d_in[4];
    const float* locbqkv = (const float*)d_in[5];
    const float* locWo = (const float*)d_in[6];
    const float* locbo = (const float*)d_in[7];
    const float* locg1 = (const float*)d_in[8];
    const float* locb1 = (const float*)d_in[9];
    const float* locW1 = (const float*)d_in[10];
    const float* locbb1 = (const float*)d_in[11];
    const float* locW2 = (const float*)d_in[12];
    const float* locbb2 = (const float*)d_in[13];
    const float* locg2 = (const float*)d_in[14];
    const float* locb2 = (const float*)d_in[15];
    const float* eWqkv = (const float*)d_in[16];
    const float* ebqkv = (const float*)d_in[17];
    const float* eWo = (const float*)d_in[18];
    const float* ebo = (const float*)d_in[19];
    const float* eg1 = (const float*)d_in[20];
    const float* eb1 = (const float*)d_in[21];
    const float* eW1 = (const float*)d_in[22];
    const float* ebb1 = (const float*)d_in[23];
    const float* eW2 = (const float*)d_in[24];
    const float* ebb2 = (const float*)d_in[25];
    const float* eg2 = (const float*)d_in[26];
    const float* eb2 = (const float*)d_in[27];
    const float* gatew = (const float*)d_in[28];
    const float* gateb = (const float*)d_in[29];
    const float* decw = (const float*)d_in[30];
    float* out = (float*)d_out;

    float* w = (float*)d_ws;
    size_t off = 0;
    auto alloc = [&](size_t n) { float* p = w + off; off += (n + 63) & ~(size_t)63; return p; };
    float* xA = alloc(1048576);
    float* xB = alloc(1048576);
    float* attnO = alloc(1048576);
    float* proj = alloc(1048576);
    float* qkv = alloc(3145728);   // also reused for decoder stats later
    float* shR = alloc(4194304);   // scores | ffn hidden (disjoint phases)
    float* xlast = alloc(4096);
    float* attnlast = alloc(4096);
    float* projlast = alloc(4096);
    float* x1last = alloc(4096);
    float* hlast = alloc(16384);
    float* flast = alloc(4096);
    float* ctxlast = alloc(4096);
    float* qlast = alloc(4096);
    float* weightsF = alloc(8192);
    float* jwp = alloc(64);
    float* impp = alloc(64);
    float* cm = qkv;                     // 1020*786 (fallback) / 1020*393 (mfma)
    float* cs = qkv + 801720;            // 1020*786
    float* ll = qkv + 1603440;           // 1020
    float* cep = qkv + 1604480;          // 1020
    // bf16 decoder buffers
    float* Xbf = alloc(524288);          // 1024*1024 bf16
    float* Wbf = alloc(25731584);        // 50257*1024 bf16
    size_t dec_need = off * sizeof(float);
    // bf16 encoder weight buffers
    float* Wqkvb = alloc(3145728);       // 2*3072*1024 bf16
    float* Wob   = alloc(1048576);       // 2*1024*1024 bf16
    float* W1b   = alloc(4194304);       // 2*4096*1024 bf16
    float* W2b   = alloc(4194304);       // 2*1024*4096 bf16
    size_t enc_need = off * sizeof(float);
    bool use_mfma = (ws_size >= dec_need);
    bool enc_mfma = (ws_size >= enc_need);

    // ---- loc layer (only last position needed downstream; Q only at last pos)
    embed_k<<<1024, 256, 0, stream>>>(inputs, emb, xA);
    copy_last_k<<<4, 256, 0, stream>>>(xA, xlast);
    // K,V columns (n in [1024,3072)) for all rows; output stride 3072
    gemm_nt_k<<<dim3(32, 16), 256, 0, stream>>>(xA, locWqkv + 1048576, locbqkv + 1024,
                                                qkv + 1024, 3072, 1024, 0);
    // Q only for the 4 last rows
    rowgemm_k<<<256, 256, 0, stream>>>(xlast, locWqkv, locbqkv, qlast, 1024, 1024, 0);
    attn_last_k<<<64, 256, 0, stream>>>(qkv, qlast, attnlast);
    rowgemm_k<<<256, 256, 0, stream>>>(attnlast, locWo, locbo, projlast, 1024, 1024, 0);
    add_ln_k<<<4, 256, 0, stream>>>(projlast, xlast, locg1, locb1, x1last, 1.0f);
    rowgemm_k<<<1024, 256, 0, stream>>>(x1last, locW1, locbb1, hlast, 4096, 1024, 1);
    rowgemm_k<<<256, 256, 0, stream>>>(hlast, locW2, locbb2, flast, 1024, 4096, 0);
    add_ln_k<<<4, 256, 0, stream>>>(flast, x1last, locg2, locb2, ctxlast, 32.0f);
    rowgemm_k<<<500, 256, 0, stream>>>(ctxlast, gatew, gateb, weightsF, 2000, 1024, 0);
    gate_stats_k<<<1, 256, 0, stream>>>(weightsF, noise, jwp, impp, out);
    qh_k<<<1024, 256, 0, stream>>>(responses, jwp, xA);

    // ---- weight conversions (bf16)
    if (use_mfma)
        cvt_bf16_k<<<2048, 256, 0, stream>>>(decw, (unsigned short*)Wbf, 12865792);
    if (enc_mfma) {
        cvt_bf16_k<<<1024, 256, 0, stream>>>(eWqkv, (unsigned short*)Wqkvb, 1572864);
        cvt_bf16_k<<<512, 256, 0, stream>>>(eWo, (unsigned short*)Wob, 524288);
        cvt_bf16_k<<<1024, 256, 0, stream>>>(eW1, (unsigned short*)W1b, 2097152);
        cvt_bf16_k<<<1024, 256, 0, stream>>>(eW2, (unsigned short*)W2b, 2097152);
    }

    // ---- 2 encoder layers (full sequence)
    for (int l = 0; l < 2; ++l) {
        const float* Wq = eWqkv + (size_t)l * 3145728;
        const float* bq = ebqkv + (size_t)l * 3072;
        const float* Wo = eWo + (size_t)l * 1048576;
        const float* bo = ebo + (size_t)l * 1024;
        const float* g1 = eg1 + (size_t)l * 1024;
        const float* b1 = eb1 + (size_t)l * 1024;
        const float* W1 = eW1 + (size_t)l * 4194304;
        const float* bb1 = ebb1 + (size_t)l * 4096;
        const float* W2 = eW2 + (size_t)l * 4194304;
        const float* bb2 = ebb2 + (size_t)l * 4096;
        const float* g2 = eg2 + (size_t)l * 1024;
        const float* b2 = eb2 + (size_t)l * 1024;
        if (enc_mfma) {
            const unsigned short* Wqb = (const unsigned short*)Wqkvb + (size_t)l * 3145728;
            const unsigned short* Wob_l = (const unsigned short*)Wob + (size_t)l * 1048576;
            const unsigned short* W1b_l = (const unsigned short*)W1b + (size_t)l * 4194304;
            const unsigned short* W2b_l = (const unsigned short*)W2b + (size_t)l * 4194304;
            gemm_mfma_k<<<dim3(24, 8), 256, 0, stream>>>(xA, Wqb, bq, qkv, 3072, 1024, 0);
            attn_scores_k<<<512, 256, 0, stream>>>(qkv, shR);
            attn_av_k<<<512, 256, 0, stream>>>(qkv, shR, attnO);
            gemm_mfma_k<<<dim3(8, 8), 256, 0, stream>>>(attnO, Wob_l, bo, proj, 1024, 1024, 0);
            add_ln_k<<<1024, 256, 0, stream>>>(proj, xA, g1, b1, xB, 1.0f);
            gemm_mfma_k<<<dim3(32, 8), 256, 0, stream>>>(xB, W1b_l, bb1, shR, 4096, 1024, 1);
            gemm_mfma_k<<<dim3(8, 8), 256, 0, stream>>>(shR, W2b_l, bb2, proj, 1024, 4096, 0);
            add_ln_k<<<1024, 256, 0, stream>>>(proj, xB, g2, b2, xA, 1.0f);
        } else {
            gemm_nt_k<<<dim3(48, 16), 256, 0, stream>>>(xA, Wq, bq, qkv, 3072, 1024, 0);
            attn_scores_k<<<512, 256, 0, stream>>>(qkv, shR);
            attn_av_k<<<512, 256, 0, stream>>>(qkv, shR, attnO);
            gemm_nt_k<<<dim3(16, 16), 256, 0, stream>>>(attnO, Wo, bo, proj, 1024, 1024, 0);
            add_ln_k<<<1024, 256, 0, stream>>>(proj, xA, g1, b1, xB, 1.0f);
            gemm_nt_k<<<dim3(64, 16), 256, 0, stream>>>(xB, W1, bb1, shR, 4096, 1024, 1);
            gemm_nt_k<<<dim3(16, 16), 256, 0, stream>>>(shR, W2, bb2, proj, 1024, 4096, 0);
            add_ln_k<<<1024, 256, 0, stream>>>(proj, xB, g2, b2, xA, 1.0f);
        }
    }

    // ---- decoder CE (streaming logsumexp, no logits materialization)
    if (use_mfma) {
        cvt_bf16_k<<<512, 256, 0, stream>>>(xA, (unsigned short*)Xbf, 262144);
        dec_mfma_k<<<dim3(8, NV2), 256, 0, stream>>>((const unsigned short*)Xbf,
                                                     (const unsigned short*)Wbf, cm, cs);
        label_logit_k<<<NTOK, 256, 0, stream>>>(xA, decw, inputs, ll);
        fin_a_k<<<NTOK, 256, 0, stream>>>(cm, cs, ll, cep, NV2);
    } else {
        dec_lse_k<<<dim3(NVT, 16), 256, 0, stream>>>(xA, decw, cm, cs);
        label_logit_k<<<NTOK, 256, 0, stream>>>(xA, decw, inputs, ll);
        fin_a_k<<<NTOK, 256, 0, stream>>>(cm, cs, ll, cep, NVT);
    }
    fin_b_k<<<1, 256, 0, stream>>>(cep, impp, out);
}